// Round 1
// 473.024 us; speedup vs baseline: 1.1620x; 1.1620x over previous
//
#include <hip/hip_runtime.h>
#include <hip/hip_bf16.h>
#include <stdint.h>

#define BB 4
#define TT 4096
#define CC 1024
#define HH 2048
#define MM (BB*TT)       // 16384 rows
#define NCK 32           // chunks along T
#define CKS 128          // chunk size

using short8 = __attribute__((ext_vector_type(8))) short;
using f32x4  = __attribute__((ext_vector_type(4))) float;

__device__ __forceinline__ unsigned short f2bf(float f) {
    union { float f; uint32_t u; } v; v.f = f;
    uint32_t r = v.u + 0x7fffu + ((v.u >> 16) & 1u);   // RNE
    return (unsigned short)(r >> 16);
}
__device__ __forceinline__ float bf_lo(uint32_t u) {
    union { uint32_t u; float f; } v; v.u = u << 16; return v.f;
}
__device__ __forceinline__ float bf_hi(uint32_t u) {
    union { uint32_t u; float f; } v; v.u = u & 0xFFFF0000u; return v.f;
}
__device__ __forceinline__ uint32_t pack2bf(float lo, float hi) {
    return ((uint32_t)f2bf(lo)) | (((uint32_t)f2bf(hi)) << 16);
}

// ---------------- prep: x fp32 -> bf16 ----------------
__global__ void conv_x_kernel(const float* __restrict__ x, unsigned short* __restrict__ xb, int n4) {
    int i = blockIdx.x * blockDim.x + threadIdx.x;
    if (i >= n4) return;
    float4 v = ((const float4*)x)[i];
    ushort4 o;
    o.x = f2bf(v.x); o.y = f2bf(v.y); o.z = f2bf(v.z); o.w = f2bf(v.w);
    ((ushort4*)xb)[i] = o;
}

// ---------------- prep: out[n][k] = in[k][n] * scale[n]  (in: R x Cin fp32) ----------------
__global__ void trans_direct_kernel(const float* __restrict__ in, unsigned short* __restrict__ out,
                                    const float* __restrict__ scale, int R, int Cin) {
    __shared__ float tile[32][33];
    int c0 = blockIdx.x * 32, k0 = blockIdx.y * 32;
    int tx = threadIdx.x;
    for (int i = threadIdx.y; i < 32; i += 8) {
        float s = scale ? scale[c0 + tx] : 1.f;
        tile[i][tx] = in[(size_t)(k0 + i) * Cin + c0 + tx] * s;
    }
    __syncthreads();
    for (int i = threadIdx.y; i < 32; i += 8)
        out[(size_t)(c0 + i) * R + k0 + tx] = f2bf(tile[tx][i]);
}

// ---------------- prep: pair-permuted W_agg^T with scale ----------------
__global__ void trans_pair_kernel(const float* __restrict__ in, unsigned short* __restrict__ out,
                                  const float* __restrict__ scale) {
    __shared__ float tile[32][33];
    int q0 = blockIdx.x * 32, k0 = blockIdx.y * 32;
    int g = q0 >> 5;
    int tx = threadIdx.x;
    int c = (tx < 16) ? (g * 16 + tx) : (2048 + g * 16 + tx - 16);
    float s = scale[c];
    for (int i = threadIdx.y; i < 32; i += 8)
        tile[i][tx] = in[(size_t)(k0 + i) * 4096 + c] * s;
    __syncthreads();
    for (int i = threadIdx.y; i < 32; i += 8)
        out[(size_t)(q0 + i) * 1024 + k0 + tx] = f2bf(tile[tx][i]);
}

// =====================================================================
// 256x256 tile, BK=32, 8 waves (2M x 4N), 4-slot LDS ring, counted vmcnt.
// Staging leads compute by 2 K-tiles: slot (t+2)&3 being written was last
// read at tile t-2, which finished >= 2 block barriers before the issue
// point -> no write-over-read race. One s_waitcnt vmcnt(4) per K-tile
// boundary keeps the next tile's 4 loads in flight across the barrier.
// LDS swizzle: physical 16B chunk p holds logical k-chunk p ^ ((row>>1)&3)
// (applied on the pre-swizzled global source AND the ds_read address).
// =====================================================================
template<int LDK, int NT>
__device__ __forceinline__ void gemm_core(
    const unsigned short* __restrict__ A,
    const unsigned short* __restrict__ Bt,
    int m0, int n0, int tid,
    f32x4 (&acc)[8][4])
{
    __shared__ __align__(16) unsigned short As[4 * 8192];   // 4 slots x 256x32
    __shared__ __align__(16) unsigned short Bs[4 * 8192];

    const int lane = tid & 63;
    const int wave = tid >> 6;
    const int l15  = lane & 15;
    const int quad = lane >> 4;
    const int wm = (wave >> 2) << 7;       // 0 or 128
    const int wn = (wave & 3) << 6;        // 0,64,128,192

#pragma unroll
    for (int i = 0; i < 8; i++)
#pragma unroll
        for (int j = 0; j < 4; j++) acc[i][j] = {0.f, 0.f, 0.f, 0.f};

    // stage-unit addressing: 512 chunks of 16B = 128 rows x 4 chunks
    const int rl  = tid >> 2;                                  // row within unit
    const int kc8 = ((tid & 3) ^ ((tid >> 3) & 3)) << 3;       // pre-swizzled k offset (shorts)
    const unsigned short* gA = A  + (size_t)(m0 + rl) * LDK + kc8;
    const unsigned short* gB = Bt + (size_t)(n0 + rl) * LDK + kc8;

#define STAGE(G, L) __builtin_amdgcn_global_load_lds( \
        (const __attribute__((address_space(1))) void*)(G), \
        (__attribute__((address_space(3))) void*)(L), 16, 0, 0)

    // prologue: stage K-tiles 0 and 1 (4 loads each)
#pragma unroll
    for (int t = 0; t < 2; t++) {
        STAGE(gA + t * 32,             &As[t * 8192 + tid * 8]);
        STAGE(gA + 128 * LDK + t * 32, &As[t * 8192 + 4096 + tid * 8]);
        STAGE(gB + t * 32,             &Bs[t * 8192 + tid * 8]);
        STAGE(gB + 128 * LDK + t * 32, &Bs[t * 8192 + 4096 + tid * 8]);
    }
    asm volatile("s_waitcnt vmcnt(4)" ::: "memory");   // tile 0 resident, tile 1 in flight
    __builtin_amdgcn_s_barrier();

    for (int t = 0; t < NT; ++t) {
        const unsigned short* as = &As[(t & 3) * 8192];
        const unsigned short* bs = &Bs[(t & 3) * 8192];
        unsigned short* asd = &As[((t + 2) & 3) * 8192];
        unsigned short* bsd = &Bs[((t + 2) & 3) * 8192];
        const bool pf = (t + 2) < NT;

        // ---- phase 0: A m-frags 0..3, all B frags; prefetch A of t+2 ----
        short8 af[4], bf[4];
#pragma unroll
        for (int i = 0; i < 4; i++) {
            int row = wm + i * 16 + l15;
            af[i] = *(const short8*)(as + row * 32 + ((quad ^ ((row >> 1) & 3)) << 3));
        }
#pragma unroll
        for (int j = 0; j < 4; j++) {
            int row = wn + j * 16 + l15;
            bf[j] = *(const short8*)(bs + row * 32 + ((quad ^ ((row >> 1) & 3)) << 3));
        }
        if (pf) {
            STAGE(gA + (t + 2) * 32,             asd + tid * 8);
            STAGE(gA + 128 * LDK + (t + 2) * 32, asd + 4096 + tid * 8);
        }
        __builtin_amdgcn_s_barrier();
        asm volatile("s_waitcnt lgkmcnt(0)" ::: "memory");
        __builtin_amdgcn_sched_barrier(0);
        __builtin_amdgcn_s_setprio(1);
#pragma unroll
        for (int i = 0; i < 4; i++)
#pragma unroll
            for (int j = 0; j < 4; j++)
                acc[i][j] = __builtin_amdgcn_mfma_f32_16x16x32_bf16(af[i], bf[j], acc[i][j], 0, 0, 0);
        __builtin_amdgcn_s_setprio(0);
        __builtin_amdgcn_sched_barrier(0);
        __builtin_amdgcn_s_barrier();

        // ---- phase 1: A m-frags 4..7 (B held in regs); prefetch B of t+2 ----
        short8 ag[4];
#pragma unroll
        for (int i = 0; i < 4; i++) {
            int row = wm + 64 + i * 16 + l15;
            ag[i] = *(const short8*)(as + row * 32 + ((quad ^ ((row >> 1) & 3)) << 3));
        }
        if (pf) {
            STAGE(gB + (t + 2) * 32,             bsd + tid * 8);
            STAGE(gB + 128 * LDK + (t + 2) * 32, bsd + 4096 + tid * 8);
        }
        __builtin_amdgcn_s_barrier();
        asm volatile("s_waitcnt lgkmcnt(0)" ::: "memory");
        __builtin_amdgcn_sched_barrier(0);
        __builtin_amdgcn_s_setprio(1);
#pragma unroll
        for (int i = 0; i < 4; i++)
#pragma unroll
            for (int j = 0; j < 4; j++)
                acc[4 + i][j] = __builtin_amdgcn_mfma_f32_16x16x32_bf16(ag[i], bf[j], acc[4 + i][j], 0, 0, 0);
        __builtin_amdgcn_s_setprio(0);
        __builtin_amdgcn_sched_barrier(0);
        // K-tile boundary: complete tile t+1's loads, keep tile t+2's in flight
        if (t < NT - 2) { asm volatile("s_waitcnt vmcnt(4)" ::: "memory"); }
        else            { asm volatile("s_waitcnt vmcnt(0)" ::: "memory"); }
        __builtin_amdgcn_s_barrier();
    }
#undef STAGE
}

// ---------------- fused GEMM: [S | poly] = x @ [W_sel' | W_aggPair'] ----------------
__global__ __launch_bounds__(512, 2) void gemm_fused_kernel(
    const unsigned short* __restrict__ A,    // 16384 x 1024 bf16
    const unsigned short* __restrict__ Bt,   // 6144 x 1024 bf16
    unsigned short* __restrict__ Sout,       // 16384 x 2048 bf16
    unsigned short* __restrict__ Pout,       // 16384 x 2048 bf16 (poly)
    float* __restrict__ part)                // B x NCK x 2048 chunk sums
{
    __shared__ float psum[256];              // [2 cks][128 poly cols]
    const int tid = threadIdx.x;
    const int mt = blockIdx.x / 24;
    const int nt = blockIdx.x % 24;
    const int m0 = mt << 8, n0 = nt << 8;
    if (tid < 256) psum[tid] = 0.f;          // visible after core's first barrier

    f32x4 acc[8][4];
    gemm_core<1024, 32>(A, Bt, m0, n0, tid, acc);

    const int lane = tid & 63;
    const int wave = tid >> 6;
    const int l15  = lane & 15;
    const int quad = lane >> 4;
    const int wm = (wave >> 2) << 7;
    const int wn = (wave & 3) << 6;

    if (nt < 8) {
        // S = silu(acc) -> bf16
#pragma unroll
        for (int i = 0; i < 8; i++)
#pragma unroll
            for (int j = 0; j < 4; j++) {
                int col = n0 + wn + j * 16 + l15;
#pragma unroll
                for (int r = 0; r < 4; r++) {
                    int row = m0 + wm + i * 16 + quad * 4 + r;
                    float v = acc[i][j][r];
                    v = v / (1.f + __expf(-v));
                    Sout[(size_t)row * 2048 + col] = f2bf(v);
                }
            }
    } else {
        // poly = h1*(1+h2); even fragment = h1, odd = h2, same poly column.
        const int pbase = ((n0 - 2048 + wn) >> 1);
        float lsum0 = 0.f, lsum1 = 0.f;
#pragma unroll
        for (int i = 0; i < 8; i++) {
#pragma unroll
            for (int jp = 0; jp < 2; jp++) {
                int pcol = pbase + jp * 16 + l15;
#pragma unroll
                for (int r = 0; r < 4; r++) {
                    int row = m0 + wm + i * 16 + quad * 4 + r;
                    float pv = acc[i][2 * jp][r] * (1.f + acc[i][2 * jp + 1][r]);
                    Pout[(size_t)row * 2048 + pcol] = f2bf(pv);
                    if (jp == 0) lsum0 += pv; else lsum1 += pv;
                }
            }
        }
        // per-chunk column sums: wave's 128 rows sit entirely in ck (wm>>7)
        int base = (wm >> 7) * 128 + (wn >> 1) + l15;
        atomicAdd(&psum[base], lsum0);
        atomicAdd(&psum[base + 16], lsum1);
        __syncthreads();
        if (tid < 256) {
            int b  = m0 >> 12;
            int ck = ((m0 & 4095) >> 7) + (tid >> 7);
            part[((size_t)b * NCK + ck) * 2048 + ((n0 - 2048) >> 1) + (tid & 127)] = psum[tid];
        }
    }
}

// ---------------- final GEMM: out = M @ W_out  (16384x2048x1024, fp32 out) ----------------
__global__ __launch_bounds__(512, 2) void gemm_out_kernel(
    const unsigned short* __restrict__ A,    // 16384 x 2048 bf16 (M)
    const unsigned short* __restrict__ Bt,   // 1024 x 2048 bf16
    float* __restrict__ Cout)
{
    const int tid = threadIdx.x;
    const int mt = blockIdx.x >> 2;
    const int nt = blockIdx.x & 3;
    const int m0 = mt << 8, n0 = nt << 8;

    f32x4 acc[8][4];
    gemm_core<2048, 64>(A, Bt, m0, n0, tid, acc);

    const int lane = tid & 63;
    const int wave = tid >> 6;
    const int l15  = lane & 15;
    const int quad = lane >> 4;
    const int wm = (wave >> 2) << 7;
    const int wn = (wave & 3) << 6;
#pragma unroll
    for (int i = 0; i < 8; i++)
#pragma unroll
        for (int j = 0; j < 4; j++) {
            int col = n0 + wn + j * 16 + l15;
#pragma unroll
            for (int r = 0; r < 4; r++) {
                int row = m0 + wm + i * 16 + quad * 4 + r;
                Cout[(size_t)row * 1024 + col] = acc[i][j][r];
            }
        }
}

// ---------------- scan phase 2: exclusive scan over chunks ----------------
__global__ void chunk_scan_kernel(float* __restrict__ part) {
    int idx = blockIdx.x * blockDim.x + threadIdx.x;   // 8192 columns
    int b = idx >> 11, col = idx & 2047;
    float run = 0.f;
    for (int ck = 0; ck < NCK; ck++) {
        size_t off = ((size_t)b * NCK + ck) * 2048 + col;
        float v = part[off];
        part[off] = run;
        run += v;
    }
}

// ---------------- scan phase 3: M = s * (cumsum/t), in place over poly ----------------
__global__ void finalize_kernel(unsigned short* __restrict__ poly, const unsigned short* __restrict__ s,
                                const float* __restrict__ part) {
    int seg = blockIdx.x & 3;
    int ck  = (blockIdx.x >> 2) & (NCK - 1);
    int b   = blockIdx.x >> 7;
    int cp  = seg * 256 + threadIdx.x;
    size_t po = ((size_t)b * NCK + ck) * 2048 + cp * 2;
    float run0 = part[po], run1 = part[po + 1];
    size_t base = ((size_t)b * TT + (size_t)ck * CKS) * 2048 + cp * 2;
    for (int t = 0; t < CKS; t++) {
        int tg = ck * CKS + t;
        size_t off = base + (size_t)t * 2048;
        uint32_t pv = *(const uint32_t*)&poly[off];
        run0 += bf_lo(pv);
        run1 += bf_hi(pv);
        float inv = 1.f / (float)(tg + 1);
        uint32_t sv = *(const uint32_t*)&s[off];
        float m0 = bf_lo(sv) * run0 * inv;
        float m1 = bf_hi(sv) * run1 * inv;
        *(uint32_t*)&poly[off] = pack2bf(m0, m1);
    }
}

extern "C" void kernel_launch(void* const* d_in, const int* in_sizes, int n_in,
                              void* d_out, int out_size, void* d_ws, size_t ws_size,
                              hipStream_t stream) {
    const float* x     = (const float*)d_in[0];
    const float* W_sel = (const float*)d_in[1];
    const float* W_agg = (const float*)d_in[2];
    const float* W_out = (const float*)d_in[3];
    const float* sqk_q = (const float*)d_in[4];
    const float* sqk_k = (const float*)d_in[5];
    float* out = (float*)d_out;

    char* ws = (char*)d_ws;
    unsigned short* xb    = (unsigned short*)(ws);                   // 32 MB
    unsigned short* wallT = (unsigned short*)(ws + 33554432ull);     // 6144x1024 bf16 (12 MB)
    unsigned short* woutT = (unsigned short*)(ws + 46137344ull);     // 1024x2048 bf16 (4 MB)
    unsigned short* s_b   = (unsigned short*)(ws + 50331648ull);     // 16384x2048 bf16 (64 MB)
    unsigned short* poly  = (unsigned short*)(ws + 117440512ull);    // 16384x2048 bf16 (64 MB)
    float*          part  = (float*)(ws + 184549376ull);             // 4x32x2048 fp32 (1 MB)

    dim3 tb(32, 8);
    conv_x_kernel<<<(MM * CC / 4 + 255) / 256, 256, 0, stream>>>(x, xb, MM * CC / 4);
    trans_direct_kernel<<<dim3(HH / 32, CC / 32), tb, 0, stream>>>(W_sel, wallT, sqk_q, CC, HH);
    trans_pair_kernel<<<dim3(4096 / 32, CC / 32), tb, 0, stream>>>(W_agg, wallT + 2048ull * 1024, sqk_k);
    trans_direct_kernel<<<dim3(CC / 32, HH / 32), tb, 0, stream>>>(W_out, woutT, nullptr, HH, CC);

    // fused: S (silu) + poly + chunk sums, one dispatch (256^2 tiles, 8-wave pipelined)
    gemm_fused_kernel<<<(MM / 256) * 24, 512, 0, stream>>>(xb, wallT, s_b, poly, part);

    chunk_scan_kernel<<<(BB * HH) / 256, 256, 0, stream>>>(part);
    finalize_kernel<<<BB * NCK * 4, 256, 0, stream>>>(poly, s_b, part);

    // out = M @ W_out (256^2 tiles, 8-wave pipelined)
    gemm_out_kernel<<<(MM / 256) * (CC / 256), 512, 0, stream>>>(poly, woutT, out);
}